// Round 6
// baseline (387.343 us; speedup 1.0000x reference)
//
#include <hip/hip_runtime.h>
#include <hip/hip_bf16.h>

// GraphEMALayer - MI355X (gfx950) - round 19: scalar-pipe edge coefficients.
// R18 counters: passA = 64.4 us @ 78% VALUBusy -- gather passes are now
// VALU-throughput bound, and most per-edge VALU is LANE-REDUNDANT:
// edge_c (cvt+rcp+mul+cmp+cndmask ~5 ops) and p1/p2 compute the same value
// in all 64 lanes. Fix: materialize cf[e] = edge_c(deg-1) ONCE (in
// fillcsr_write, bitwise-identical expression) and let the passes fetch it
// over the SCALAR pipe (s_load; j is readfirstlane'd): per-edge per-lane
// VALU drops ~17 -> ~6 (A) / ~3 (B,C,D). alpha in A via SALU s_cselect
// from the packed deg bits. Results bitwise identical to R18.
// cf lives in d_out[12.8,19.2) MB (dead until pass D overwrites); pass D
// reads a copy (cfD) placed in hbf's slot, which dies after pass A
// (ema_cfcopy, 6.4 MB, ~2 us). Everything else unchanged. WS 60.0 MB.

static __device__ __forceinline__ float bf2f(unsigned short v) {
    union { unsigned int u; float f; } x;
    x.u = ((unsigned int)v) << 16;
    return x.f;
}

static __device__ __forceinline__ unsigned short f2bf(float f) {
    union { unsigned int u; float f; } x;
    x.f = f;
    unsigned int r = x.u + 0x7FFFu + ((x.u >> 16) & 1u);
    return (unsigned short)(r >> 16);
}

// c from packed dm1: 0.5*rcp(dm1); exact 0 for leaves (dm1==0).
static __device__ __forceinline__ float edge_c(int dm1) {
    float fd = (float)dm1;
    float raw = 0.5f * __builtin_amdgcn_rcpf(fd);
    return (fd == 0.0f) ? 0.0f : raw;
}

// h = x@W + b -> bf16 shadow. Wave = 8 nodes, lane = column.
__global__ void ema_gemm_kernel(const float* __restrict__ x, const float* __restrict__ W,
                                const float* __restrict__ bias, unsigned short* __restrict__ hbf) {
    int wave = (int)((blockIdx.x * 256 + threadIdx.x) >> 6);
    int lane = (int)(threadIdx.x & 63);
    int n0 = wave * 8;
    if (n0 >= 100000) return;
    float w[64];
    #pragma unroll
    for (int k = 0; k < 64; ++k) w[k] = W[k * 64 + lane];   // coalesced, L1-hot
    float bv = bias[lane];
    int nend = (n0 + 8 < 100000) ? (n0 + 8) : 100000;
    for (int n = n0; n < nend; ++n) {
        const float* xr = x + (size_t)__builtin_amdgcn_readfirstlane(n) * 64;
        float acc = bv;
        #pragma unroll
        for (int k = 0; k < 64; ++k) acc = fmaf(xr[k], w[k], acc);
        hbf[n * 64 + lane] = f2bf(acc);
    }
}

// Step 1: per-block bucket histogram. Block bl owns edges
// [bl*4096, bl*4096+4096); LDS atomics only; hcnt[bucket*391 + bl].
__global__ void ema_hist_kernel(const int* ei, int* hcnt) {
    __shared__ int hist[391];
    int t = (int)threadIdx.x;
    int bl = (int)blockIdx.x;
    for (int i = t; i < 391; i += 256) hist[i] = 0;
    __syncthreads();
    int e0 = bl * 4096;
    #pragma unroll
    for (int i = 0; i < 16; ++i) {
        int e = e0 + t + i * 256;
        if (e < 1600000) {
            int dst = (e < 800000) ? ei[e + 800000] : ei[e - 800000];
            atomicAdd(&hist[dst >> 8], 1);
        }
    }
    __syncthreads();
    for (int i = t; i < 391; i += 256) hcnt[i * 391 + bl] = hist[i];
}

// Step 2a: per-bucket row: exclusive scan of 391 block counts (no base),
// and emit the row total.
__global__ void ema_bscan_row_kernel(int* hcnt, int* btot) {
    __shared__ int s[512];
    int bu = (int)blockIdx.x;
    int t = (int)threadIdx.x;
    int v = (t < 391) ? hcnt[bu * 391 + t] : 0;
    s[t] = v;
    __syncthreads();
    for (int off = 1; off < 512; off <<= 1) {
        int add = (t >= off) ? s[t - off] : 0;
        __syncthreads();
        s[t] += add;
        __syncthreads();
    }
    if (t < 391) hcnt[bu * 391 + t] = s[t] - v;
    if (t == 390) btot[bu] = s[t];
}

// Step 2b: single block: exclusive scan of bucket totals -> bbase[0..391].
__global__ void ema_bscan_base_kernel(const int* btot, int* bbase) {
    __shared__ int s[512];
    int t = (int)threadIdx.x;
    int v = (t < 391) ? btot[t] : 0;
    s[t] = v;
    __syncthreads();
    for (int off = 1; off < 512; off <<= 1) {
        int add = (t >= off) ? s[t - off] : 0;
        __syncthreads();
        s[t] += add;
        __syncthreads();
    }
    if (t < 391) bbase[t] = s[t] - v;
    if (t == 390) bbase[391] = s[t];
}

// Step 3: scatter into stage at per-(bucket,block) bases (row scan + bbase).
__global__ void ema_scatter_kernel(const int* ei, const int* hcnt,
                                   const int* bbase, unsigned int* stage) {
    __shared__ int base[391];
    __shared__ int cnt[391];
    int t = (int)threadIdx.x;
    int bl = (int)blockIdx.x;
    for (int i = t; i < 391; i += 256) {
        base[i] = hcnt[i * 391 + bl] + bbase[i];
        cnt[i] = 0;
    }
    __syncthreads();
    int e0 = bl * 4096;
    #pragma unroll
    for (int i = 0; i < 16; ++i) {
        int e = e0 + t + i * 256;
        if (e < 1600000) {
            int src = ei[e];
            int dst = (e < 800000) ? ei[e + 800000] : ei[e - 800000];
            int bu = dst >> 8;
            int slot = base[bu] + atomicAdd(&cnt[bu], 1);
            stage[slot] = ((unsigned int)(dst & 255) << 24) | (unsigned int)src;
        }
    }
}

// Step 4a: one block per bucket: count the 256 local ids over the stage
// segment (LDS atomics), block exclusive scan -> degi[] and rs[].
__global__ void ema_fillcsr_count_kernel(const int* __restrict__ bbase,
                                         const unsigned int* __restrict__ stage,
                                         int* __restrict__ degi,
                                         int* __restrict__ rs) {
    __shared__ int cnt[256];
    __shared__ int scn[256];
    int b = (int)blockIdx.x;
    int t = (int)threadIdx.x;
    cnt[t] = 0;
    __syncthreads();
    int seg_lo = bbase[b];
    int seg_hi = bbase[b + 1];
    for (int i = seg_lo + t; i < seg_hi; i += 256) {
        atomicAdd(&cnt[stage[i] >> 24], 1);
    }
    __syncthreads();
    int v = cnt[t];
    scn[t] = v;
    __syncthreads();
    for (int off = 1; off < 256; off <<= 1) {
        int add = (t >= off) ? scn[t - off] : 0;
        __syncthreads();
        scn[t] += add;
        __syncthreads();
    }
    int node = (b << 8) + t;
    if (node < 100000) {
        degi[node] = v;
        rs[node] = seg_lo + scn[t] - v;
    }
}

// Step 4b: one block per bucket; LDS per-node slots; writes PACKED csr
// ((deg-1)<<17|idx) AND the per-edge f32 coefficient cf (scalar-pipe
// stream for the gather passes).
__global__ void ema_fillcsr_write_kernel(const int* __restrict__ rs,
                                         const unsigned int* __restrict__ stage,
                                         const int* __restrict__ degi,
                                         int* __restrict__ csr,
                                         float* __restrict__ cf) {
    __shared__ int rsl[256];
    __shared__ int cnt[256];
    int b = (int)blockIdx.x;
    int t = (int)threadIdx.x;
    int node_lo = b << 8;
    int node = node_lo + t;
    rsl[t] = (node < 100000) ? rs[node] : 1600000;
    cnt[t] = 0;
    __syncthreads();
    int seg_lo = rsl[0];
    int seg_hi = (node_lo + 256 < 100000) ? rs[node_lo + 256] : 1600000;
    for (int i = seg_lo + t; i < seg_hi; i += 256) {
        unsigned int v = stage[i];
        int local = (int)(v >> 24);
        int srcn = (int)(v & 0x00FFFFFFu);
        int dm1 = degi[srcn] - 1;
        if (dm1 < 0) dm1 = 0;
        if (dm1 > 32767) dm1 = 32767;
        int slot = rsl[local] + atomicAdd(&cnt[local], 1);
        csr[slot] = (dm1 << 17) | srcn;
        cf[slot] = edge_c(dm1);
    }
}

// cf copy for pass D: cf lives in d_out (clobbered by D's output writes);
// hbf's slot is dead after pass A -> copy there.
__global__ void ema_cfcopy_kernel(const float4* __restrict__ cf4,
                                  float4* __restrict__ cfD4) {
    int i = (int)(blockIdx.x * 256 + threadIdx.x);
    if (i < 400000) cfD4[i] = cf4[i];
}

// Pass A: gather hbf rows; emit m0, W1, W2, W3a and pp=(r c P1, r c).
__global__ void ema_passA_kernel(const int* __restrict__ degi, const int* __restrict__ rs,
                                 const int* __restrict__ csr, const float* __restrict__ cf,
                                 const unsigned short* __restrict__ hbf,
                                 unsigned short* __restrict__ m0, unsigned short* __restrict__ W1,
                                 unsigned short* __restrict__ W2, unsigned short* __restrict__ W3a,
                                 float2* __restrict__ pp) {
    int wid = (int)((blockIdx.x * 256 + threadIdx.x) >> 6);
    int c = (int)(threadIdx.x & 63);
    if (wid >= 100000) return;
    int dv = __builtin_amdgcn_readfirstlane(degi[wid]);
    int base = wid * 64 + c;
    float hv = bf2f(hbf[base]);
    if (dv == 0) {
        m0[base] = 0;
        W1[base] = 0;
        W2[base] = 0;
        W3a[base] = f2bf(hv);   // y = h for isolated nodes
        if (c == 0) pp[wid] = make_float2(0.0f, 0.0f);
        return;
    }
    int j = __builtin_amdgcn_readfirstlane(rs[wid]);
    int end = j + dv;
    float av = (dv > 1) ? 0.5f : 1.0f;
    float cv = (dv > 1) ? 0.5f / ((float)dv - 1.0f + 1e-9f) : 0.0f;
    float fv = av * hv;
    float sm = 0.0f, sS = 0.0f, sQ = 0.0f, p1 = 0.0f, p2 = 0.0f;
    for (; j + 4 <= end; j += 4) {
        unsigned int w0 = (unsigned int)csr[j];
        unsigned int w1 = (unsigned int)csr[j + 1];
        unsigned int w2 = (unsigned int)csr[j + 2];
        unsigned int w3 = (unsigned int)csr[j + 3];
        int a0 = (int)(w0 & 0x1FFFFu), d0 = (int)(w0 >> 17);
        int a1 = (int)(w1 & 0x1FFFFu), d1 = (int)(w1 >> 17);
        int a2 = (int)(w2 & 0x1FFFFu), d2 = (int)(w2 >> 17);
        int a3 = (int)(w3 & 0x1FFFFu), d3 = (int)(w3 >> 17);
        float c0 = cf[j], c1 = cf[j + 1], c2 = cf[j + 2], c3 = cf[j + 3];
        float h0 = bf2f(hbf[a0 * 64 + c]);
        float h1 = bf2f(hbf[a1 * 64 + c]);
        float h2 = bf2f(hbf[a2 * 64 + c]);
        float h3 = bf2f(hbf[a3 * 64 + c]);
        float al0 = d0 ? 0.5f : 1.0f;   // scalar: d0 is SGPR -> s_cselect
        float al1 = d1 ? 0.5f : 1.0f;
        float al2 = d2 ? 0.5f : 1.0f;
        float al3 = d3 ? 0.5f : 1.0f;
        sm += (h0 + h1) + (h2 + h3);
        sS += al0 * h0 + al1 * h1 + al2 * h2 + al3 * h3;
        sQ += c0 * h0 + c1 * h1 + c2 * h2 + c3 * h3;
        p1 += (c0 + c1) + (c2 + c3);
        p2 += c0 * c0 + c1 * c1 + c2 * c2 + c3 * c3;
    }
    for (; j < end; ++j) {
        unsigned int w0 = (unsigned int)csr[j];
        int a = (int)(w0 & 0x1FFFFu), d0 = (int)(w0 >> 17);
        float ha = bf2f(hbf[a * 64 + c]);
        float ca = cf[j];
        float ala = d0 ? 0.5f : 1.0f;
        sm += ha;
        sS += ala * ha;
        sQ += ca * ha;
        p1 += ca;
        p2 += ca * ca;
    }
    float r = 0.5f / ((float)dv + 1e-9f);
    float w1o = sS - hv * p1;
    float w2o = sS - fv * p1 - cv * p1 * sm + cv * sQ;
    float w3o = 0.5f * hv + r * (sS - fv * p1 + 0.5f * cv * sQ - cv * hv * p2);
    m0[base] = f2bf(sm);
    W1[base] = f2bf(w1o);
    W2[base] = f2bf(w2o);
    W3a[base] = f2bf(w3o);
    if (c == 0) pp[wid] = make_float2(r * cv * p1, r * cv);
}

// Pass B: gather m0 rows; m1 = W1 + sum c_a m0[a] (in place over W1);
// W4 = W3a - pp.x*m1 + pp.y*U, U = sum c_a^2 m0[a] (in place over W3a).
__global__ void ema_passB_kernel(const int* __restrict__ degi, const int* __restrict__ rs,
                                 const int* __restrict__ csr, const float* __restrict__ cf,
                                 const unsigned short* __restrict__ m0,
                                 unsigned short* __restrict__ W1m1, unsigned short* __restrict__ W3W4,
                                 const float2* __restrict__ pp) {
    int wid = (int)((blockIdx.x * 256 + threadIdx.x) >> 6);
    int c = (int)(threadIdx.x & 63);
    if (wid >= 100000) return;
    int dv = __builtin_amdgcn_readfirstlane(degi[wid]);
    if (dv == 0) return;   // slots already hold m1=0, W4=h from pass A
    int base = wid * 64 + c;
    int j = __builtin_amdgcn_readfirstlane(rs[wid]);
    int end = j + dv;
    float t1 = 0.0f, t2 = 0.0f;
    for (; j + 4 <= end; j += 4) {
        unsigned int w0 = (unsigned int)csr[j];
        unsigned int w1 = (unsigned int)csr[j + 1];
        unsigned int w2 = (unsigned int)csr[j + 2];
        unsigned int w3 = (unsigned int)csr[j + 3];
        int a0 = (int)(w0 & 0x1FFFFu);
        int a1 = (int)(w1 & 0x1FFFFu);
        int a2 = (int)(w2 & 0x1FFFFu);
        int a3 = (int)(w3 & 0x1FFFFu);
        float c0 = cf[j], c1 = cf[j + 1], c2 = cf[j + 2], c3 = cf[j + 3];
        float m0v = bf2f(m0[a0 * 64 + c]);
        float m1v = bf2f(m0[a1 * 64 + c]);
        float m2v = bf2f(m0[a2 * 64 + c]);
        float m3v = bf2f(m0[a3 * 64 + c]);
        t1 += c0 * m0v + c1 * m1v + c2 * m2v + c3 * m3v;
        t2 += c0 * c0 * m0v + c1 * c1 * m1v + c2 * c2 * m2v + c3 * c3 * m3v;
    }
    for (; j < end; ++j) {
        unsigned int w0 = (unsigned int)csr[j];
        int a = (int)(w0 & 0x1FFFFu);
        float ca = cf[j];
        float mv = bf2f(m0[a * 64 + c]);
        t1 += ca * mv;
        t2 += ca * ca * mv;
    }
    float2 ppv = pp[wid];
    float m1 = bf2f(W1m1[base]) + t1;
    float w4 = bf2f(W3W4[base]) - ppv.x * m1 + ppv.y * t2;
    W1m1[base] = f2bf(m1);
    W3W4[base] = f2bf(w4);
}

// Pass C: gather m1 rows; m2 = W2 + sum c_a m1[a] (in place over W2).
__global__ void ema_passC_kernel(const int* __restrict__ degi, const int* __restrict__ rs,
                                 const int* __restrict__ csr, const float* __restrict__ cf,
                                 const unsigned short* __restrict__ m1,
                                 unsigned short* __restrict__ W2m2) {
    int wid = (int)((blockIdx.x * 256 + threadIdx.x) >> 6);
    int c = (int)(threadIdx.x & 63);
    if (wid >= 100000) return;
    int dv = __builtin_amdgcn_readfirstlane(degi[wid]);
    if (dv == 0) return;   // slot already holds m2=0
    int base = wid * 64 + c;
    int j = __builtin_amdgcn_readfirstlane(rs[wid]);
    int end = j + dv;
    float t = 0.0f;
    for (; j + 4 <= end; j += 4) {
        unsigned int w0 = (unsigned int)csr[j];
        unsigned int w1 = (unsigned int)csr[j + 1];
        unsigned int w2 = (unsigned int)csr[j + 2];
        unsigned int w3 = (unsigned int)csr[j + 3];
        int a0 = (int)(w0 & 0x1FFFFu);
        int a1 = (int)(w1 & 0x1FFFFu);
        int a2 = (int)(w2 & 0x1FFFFu);
        int a3 = (int)(w3 & 0x1FFFFu);
        float c0 = cf[j], c1 = cf[j + 1], c2 = cf[j + 2], c3 = cf[j + 3];
        float m0v = bf2f(m1[a0 * 64 + c]);
        float m1v = bf2f(m1[a1 * 64 + c]);
        float m2v = bf2f(m1[a2 * 64 + c]);
        float m3v = bf2f(m1[a3 * 64 + c]);
        t += c0 * m0v + c1 * m1v + c2 * m2v + c3 * m3v;
    }
    for (; j < end; ++j) {
        unsigned int w0 = (unsigned int)csr[j];
        int a = (int)(w0 & 0x1FFFFu);
        t += cf[j] * bf2f(m1[a * 64 + c]);
    }
    float m2v = bf2f(W2m2[base]) + t;
    W2m2[base] = f2bf(m2v);
}

// Pass D (identifier kernel): gather m2 rows; y = W4 + r*sum c_a m2[a];
// out = x + relu(y). Overwrites all of d_out (m0 + cf regions are dead;
// reads cfD, the copy in hbf's slot).
__global__ void GraphEMALayer_18133351924067_kernel(
    const int* __restrict__ degi, const int* __restrict__ rs,
    const int* __restrict__ csr, const float* __restrict__ cfD,
    const unsigned short* __restrict__ m2, const unsigned short* __restrict__ W4,
    const float* __restrict__ x, float* __restrict__ out) {
    int wid = (int)((blockIdx.x * 256 + threadIdx.x) >> 6);
    int c = (int)(threadIdx.x & 63);
    if (wid >= 100000) return;
    int dv = __builtin_amdgcn_readfirstlane(degi[wid]);
    int base = wid * 64 + c;
    float xv = x[base];
    float y = bf2f(W4[base]);
    if (dv > 0) {
        int j = __builtin_amdgcn_readfirstlane(rs[wid]);
        int end = j + dv;
        float t = 0.0f;
        for (; j + 4 <= end; j += 4) {
            unsigned int w0 = (unsigned int)csr[j];
            unsigned int w1 = (unsigned int)csr[j + 1];
            unsigned int w2 = (unsigned int)csr[j + 2];
            unsigned int w3 = (unsigned int)csr[j + 3];
            int a0 = (int)(w0 & 0x1FFFFu);
            int a1 = (int)(w1 & 0x1FFFFu);
            int a2 = (int)(w2 & 0x1FFFFu);
            int a3 = (int)(w3 & 0x1FFFFu);
            float c0 = cfD[j], c1 = cfD[j + 1], c2 = cfD[j + 2], c3 = cfD[j + 3];
            float m0v = bf2f(m2[a0 * 64 + c]);
            float m1v = bf2f(m2[a1 * 64 + c]);
            float m2v = bf2f(m2[a2 * 64 + c]);
            float m3v = bf2f(m2[a3 * 64 + c]);
            t += c0 * m0v + c1 * m1v + c2 * m2v + c3 * m3v;
        }
        for (; j < end; ++j) {
            unsigned int w0 = (unsigned int)csr[j];
            int a = (int)(w0 & 0x1FFFFu);
            t += cfD[j] * bf2f(m2[a * 64 + c]);
        }
        float r = 0.5f / ((float)dv + 1e-9f);
        y += r * t;
    }
    if (y < 0.0f) y = 0.0f;
    out[base] = xv + y;
}

extern "C" void kernel_launch(void* const* d_in, const int* in_sizes, int n_in,
                              void* d_out, int out_size, void* d_ws, size_t ws_size,
                              hipStream_t stream) {
    (void)in_sizes; (void)n_in; (void)out_size; (void)ws_size;

    const float* x    = (const float*)d_in[0];
    const int*   ei   = (const int*)d_in[1];
    const float* W    = (const float*)d_in[2];
    const float* bias = (const float*)d_in[3];
    float* out = (float*)d_out;
    unsigned short* m0 = (unsigned short*)d_out;   // first 12.8 MB, dead before D
    float* cf = (float*)((char*)d_out + 12800000); // 6.4 MB, dead before D

    char* ws = (char*)d_ws;
    unsigned short* hbf  = (unsigned short*)(ws);             // 12,800,000 B
    unsigned short* W1m1 = (unsigned short*)(ws + 12800000);  // 12,800,000 B
    unsigned short* W2m2 = (unsigned short*)(ws + 25600000);  // 12,800,000 B
    unsigned short* W3W4 = (unsigned short*)(ws + 38400000);  // 12,800,000 B
    int* degi = (int*)(ws + 51200000);                        //    400,000 B
    int* rs   = (int*)(ws + 51600000);                        //    400,000 B
    float2* pp   = (float2*)(ws + 52800000);                  //    800,000 B
    int* csr  = (int*)(ws + 53600000);                        //  6,400,000 B
    int* bbase = (int*)(ws + 60000000);                       //      1,568 B
    int* btot  = (int*)(ws + 60002048);                       //      1,564 B

    // CSR-build scratch, both dead before pass A writes them:
    unsigned int* stage = (unsigned int*)(ws + 12800000);     // aliases W1m1, 6.4 MB
    int* hcnt = (int*)(ws + 25600000);                        // aliases W2m2, 611,524 B
    float* cfD = (float*)(ws);                                // aliases hbf (dead after A)

    int eb = (100000 * 64 + 255) / 256;   // 25000 blocks: wave-per-node grids
    int nb = (100000 + 255) / 256;        //   391 blocks: per-bucket grids
    int pb = (1600000 + 4095) / 4096;     //   391 blocks: partition grids
    int gb = (100000 + 31) / 32;          //  3125 blocks: gemm (32 nodes/block)
    int cb = (400000 + 255) / 256;        //  1563 blocks: cf copy (float4)

    ema_gemm_kernel<<<gb, 256, 0, stream>>>(x, W, bias, hbf);

    ema_hist_kernel<<<pb, 256, 0, stream>>>(ei, hcnt);
    ema_bscan_row_kernel<<<391, 512, 0, stream>>>(hcnt, btot);
    ema_bscan_base_kernel<<<1, 512, 0, stream>>>(btot, bbase);
    ema_scatter_kernel<<<pb, 256, 0, stream>>>(ei, hcnt, bbase, stage);
    ema_fillcsr_count_kernel<<<nb, 256, 0, stream>>>(bbase, stage, degi, rs);
    ema_fillcsr_write_kernel<<<nb, 256, 0, stream>>>(rs, stage, degi, csr, cf);

    ema_passA_kernel<<<eb, 256, 0, stream>>>(degi, rs, csr, cf, hbf,
                                             m0, W1m1, W2m2, W3W4, pp);
    ema_cfcopy_kernel<<<cb, 256, 0, stream>>>((const float4*)cf, (float4*)cfD);
    ema_passB_kernel<<<eb, 256, 0, stream>>>(degi, rs, csr, cf, m0,
                                             W1m1, W3W4, pp);
    ema_passC_kernel<<<eb, 256, 0, stream>>>(degi, rs, csr, cf, W1m1, W2m2);
    GraphEMALayer_18133351924067_kernel<<<eb, 256, 0, stream>>>(
        degi, rs, csr, cfD, W2m2, W3W4, x, out);
}

// Round 7
// 364.558 us; speedup vs baseline: 1.0625x; 1.0625x over previous
//
#include <hip/hip_runtime.h>
#include <hip/hip_bf16.h>

// GraphEMALayer - MI355X (gfx950) - round 20: streaming cf + 8-wide gather MLP.
// R19 post-mortem: net +10 us. passA improved (64->60 us, VALU 78->63%) but
// fillcsr_write absorbed the win (per-edge rcp + a SECOND scattered 4B store).
// Counters say passes are latency-bound (32% HBM, 63% VALU, 69% occ): with
// avg deg 16 and 4-wide unroll a wave has only ~4 chunks and 4 gathers in
// flight. Fixes:
//   - ema_cfgen: cf generated by a LINEAR pass over packed csr (coalesced
//     6.4MB r + 6.4MB w, ~3 us); fillcsr_write reverts to csr-only (R18).
//     cfD copy for pass D (into dead hbf) stays after passA.
//   - all 4 gather passes: 8-wide chunks -> 8 s_loaded csr/cf entries,
//     8 outstanding global_load_ushort row gathers, ONE vmcnt wait per
//     chunk; 4-wide + scalar tails. Doubles per-wave MLP, VGPR ~32.
// Values bitwise identical to R19. Workspace 60.0 MB.

static __device__ __forceinline__ float bf2f(unsigned short v) {
    union { unsigned int u; float f; } x;
    x.u = ((unsigned int)v) << 16;
    return x.f;
}

static __device__ __forceinline__ unsigned short f2bf(float f) {
    union { unsigned int u; float f; } x;
    x.f = f;
    unsigned int r = x.u + 0x7FFFu + ((x.u >> 16) & 1u);
    return (unsigned short)(r >> 16);
}

// c from packed dm1: 0.5*rcp(dm1); exact 0 for leaves (dm1==0).
static __device__ __forceinline__ float edge_c(int dm1) {
    float fd = (float)dm1;
    float raw = 0.5f * __builtin_amdgcn_rcpf(fd);
    return (fd == 0.0f) ? 0.0f : raw;
}

// h = x@W + b -> bf16 shadow. Wave = 8 nodes, lane = column.
__global__ void ema_gemm_kernel(const float* __restrict__ x, const float* __restrict__ W,
                                const float* __restrict__ bias, unsigned short* __restrict__ hbf) {
    int wave = (int)((blockIdx.x * 256 + threadIdx.x) >> 6);
    int lane = (int)(threadIdx.x & 63);
    int n0 = wave * 8;
    if (n0 >= 100000) return;
    float w[64];
    #pragma unroll
    for (int k = 0; k < 64; ++k) w[k] = W[k * 64 + lane];   // coalesced, L1-hot
    float bv = bias[lane];
    int nend = (n0 + 8 < 100000) ? (n0 + 8) : 100000;
    for (int n = n0; n < nend; ++n) {
        const float* xr = x + (size_t)__builtin_amdgcn_readfirstlane(n) * 64;
        float acc = bv;
        #pragma unroll
        for (int k = 0; k < 64; ++k) acc = fmaf(xr[k], w[k], acc);
        hbf[n * 64 + lane] = f2bf(acc);
    }
}

// Step 1: per-block bucket histogram. Block bl owns edges
// [bl*4096, bl*4096+4096); LDS atomics only; hcnt[bucket*391 + bl].
__global__ void ema_hist_kernel(const int* ei, int* hcnt) {
    __shared__ int hist[391];
    int t = (int)threadIdx.x;
    int bl = (int)blockIdx.x;
    for (int i = t; i < 391; i += 256) hist[i] = 0;
    __syncthreads();
    int e0 = bl * 4096;
    #pragma unroll
    for (int i = 0; i < 16; ++i) {
        int e = e0 + t + i * 256;
        if (e < 1600000) {
            int dst = (e < 800000) ? ei[e + 800000] : ei[e - 800000];
            atomicAdd(&hist[dst >> 8], 1);
        }
    }
    __syncthreads();
    for (int i = t; i < 391; i += 256) hcnt[i * 391 + bl] = hist[i];
}

// Step 2a: per-bucket row: exclusive scan of 391 block counts (no base),
// and emit the row total.
__global__ void ema_bscan_row_kernel(int* hcnt, int* btot) {
    __shared__ int s[512];
    int bu = (int)blockIdx.x;
    int t = (int)threadIdx.x;
    int v = (t < 391) ? hcnt[bu * 391 + t] : 0;
    s[t] = v;
    __syncthreads();
    for (int off = 1; off < 512; off <<= 1) {
        int add = (t >= off) ? s[t - off] : 0;
        __syncthreads();
        s[t] += add;
        __syncthreads();
    }
    if (t < 391) hcnt[bu * 391 + t] = s[t] - v;
    if (t == 390) btot[bu] = s[t];
}

// Step 2b: single block: exclusive scan of bucket totals -> bbase[0..391].
__global__ void ema_bscan_base_kernel(const int* btot, int* bbase) {
    __shared__ int s[512];
    int t = (int)threadIdx.x;
    int v = (t < 391) ? btot[t] : 0;
    s[t] = v;
    __syncthreads();
    for (int off = 1; off < 512; off <<= 1) {
        int add = (t >= off) ? s[t - off] : 0;
        __syncthreads();
        s[t] += add;
        __syncthreads();
    }
    if (t < 391) bbase[t] = s[t] - v;
    if (t == 390) bbase[391] = s[t];
}

// Step 3: scatter into stage at per-(bucket,block) bases (row scan + bbase).
__global__ void ema_scatter_kernel(const int* ei, const int* hcnt,
                                   const int* bbase, unsigned int* stage) {
    __shared__ int base[391];
    __shared__ int cnt[391];
    int t = (int)threadIdx.x;
    int bl = (int)blockIdx.x;
    for (int i = t; i < 391; i += 256) {
        base[i] = hcnt[i * 391 + bl] + bbase[i];
        cnt[i] = 0;
    }
    __syncthreads();
    int e0 = bl * 4096;
    #pragma unroll
    for (int i = 0; i < 16; ++i) {
        int e = e0 + t + i * 256;
        if (e < 1600000) {
            int src = ei[e];
            int dst = (e < 800000) ? ei[e + 800000] : ei[e - 800000];
            int bu = dst >> 8;
            int slot = base[bu] + atomicAdd(&cnt[bu], 1);
            stage[slot] = ((unsigned int)(dst & 255) << 24) | (unsigned int)src;
        }
    }
}

// Step 4a: one block per bucket: count the 256 local ids over the stage
// segment (LDS atomics), block exclusive scan -> degi[] and rs[].
__global__ void ema_fillcsr_count_kernel(const int* __restrict__ bbase,
                                         const unsigned int* __restrict__ stage,
                                         int* __restrict__ degi,
                                         int* __restrict__ rs) {
    __shared__ int cnt[256];
    __shared__ int scn[256];
    int b = (int)blockIdx.x;
    int t = (int)threadIdx.x;
    cnt[t] = 0;
    __syncthreads();
    int seg_lo = bbase[b];
    int seg_hi = bbase[b + 1];
    for (int i = seg_lo + t; i < seg_hi; i += 256) {
        atomicAdd(&cnt[stage[i] >> 24], 1);
    }
    __syncthreads();
    int v = cnt[t];
    scn[t] = v;
    __syncthreads();
    for (int off = 1; off < 256; off <<= 1) {
        int add = (t >= off) ? scn[t - off] : 0;
        __syncthreads();
        scn[t] += add;
        __syncthreads();
    }
    int node = (b << 8) + t;
    if (node < 100000) {
        degi[node] = v;
        rs[node] = seg_lo + scn[t] - v;
    }
}

// Step 4b: one block per bucket; LDS per-node slots; writes PACKED csr
// ((min(deg-1,32767))<<17 | idx). csr-only scattered writes (R18 form).
__global__ void ema_fillcsr_write_kernel(const int* __restrict__ rs,
                                         const unsigned int* __restrict__ stage,
                                         const int* __restrict__ degi,
                                         int* __restrict__ csr) {
    __shared__ int rsl[256];
    __shared__ int cnt[256];
    int b = (int)blockIdx.x;
    int t = (int)threadIdx.x;
    int node_lo = b << 8;
    int node = node_lo + t;
    rsl[t] = (node < 100000) ? rs[node] : 1600000;
    cnt[t] = 0;
    __syncthreads();
    int seg_lo = rsl[0];
    int seg_hi = (node_lo + 256 < 100000) ? rs[node_lo + 256] : 1600000;
    for (int i = seg_lo + t; i < seg_hi; i += 256) {
        unsigned int v = stage[i];
        int local = (int)(v >> 24);
        int srcn = (int)(v & 0x00FFFFFFu);
        int dm1 = degi[srcn] - 1;
        if (dm1 < 0) dm1 = 0;
        if (dm1 > 32767) dm1 = 32767;
        int slot = rsl[local] + atomicAdd(&cnt[local], 1);
        csr[slot] = (dm1 << 17) | srcn;
    }
}

// cf generation: LINEAR pass over packed csr (coalesced read + write).
__global__ void ema_cfgen_kernel(const int* __restrict__ csr,
                                 float* __restrict__ cf) {
    int i = (int)(blockIdx.x * 256 + threadIdx.x);
    if (i < 1600000) cf[i] = edge_c(((unsigned int)csr[i]) >> 17);
}

// cf copy for pass D: cf lives in d_out (clobbered by D's output writes);
// hbf's slot is dead after pass A -> copy there.
__global__ void ema_cfcopy_kernel(const float4* __restrict__ cf4,
                                  float4* __restrict__ cfD4) {
    int i = (int)(blockIdx.x * 256 + threadIdx.x);
    if (i < 400000) cfD4[i] = cf4[i];
}

// Pass A: gather hbf rows; emit m0, W1, W2, W3a and pp=(r c P1, r c).
__global__ void ema_passA_kernel(const int* __restrict__ degi, const int* __restrict__ rs,
                                 const int* __restrict__ csr, const float* __restrict__ cf,
                                 const unsigned short* __restrict__ hbf,
                                 unsigned short* __restrict__ m0, unsigned short* __restrict__ W1,
                                 unsigned short* __restrict__ W2, unsigned short* __restrict__ W3a,
                                 float2* __restrict__ pp) {
    int wid = (int)((blockIdx.x * 256 + threadIdx.x) >> 6);
    int c = (int)(threadIdx.x & 63);
    if (wid >= 100000) return;
    int dv = __builtin_amdgcn_readfirstlane(degi[wid]);
    int base = wid * 64 + c;
    float hv = bf2f(hbf[base]);
    if (dv == 0) {
        m0[base] = 0;
        W1[base] = 0;
        W2[base] = 0;
        W3a[base] = f2bf(hv);   // y = h for isolated nodes
        if (c == 0) pp[wid] = make_float2(0.0f, 0.0f);
        return;
    }
    int j = __builtin_amdgcn_readfirstlane(rs[wid]);
    int end = j + dv;
    float av = (dv > 1) ? 0.5f : 1.0f;
    float cv = (dv > 1) ? 0.5f / ((float)dv - 1.0f + 1e-9f) : 0.0f;
    float fv = av * hv;
    float sm = 0.0f, sS = 0.0f, sQ = 0.0f, p1 = 0.0f, p2 = 0.0f;
    for (; j + 8 <= end; j += 8) {
        unsigned int w0 = (unsigned int)csr[j],     w1 = (unsigned int)csr[j + 1];
        unsigned int w2 = (unsigned int)csr[j + 2], w3 = (unsigned int)csr[j + 3];
        unsigned int w4 = (unsigned int)csr[j + 4], w5 = (unsigned int)csr[j + 5];
        unsigned int w6 = (unsigned int)csr[j + 6], w7 = (unsigned int)csr[j + 7];
        float c0 = cf[j],     c1 = cf[j + 1], c2 = cf[j + 2], c3 = cf[j + 3];
        float c4 = cf[j + 4], c5 = cf[j + 5], c6 = cf[j + 6], c7 = cf[j + 7];
        float h0 = bf2f(hbf[(int)(w0 & 0x1FFFFu) * 64 + c]);
        float h1 = bf2f(hbf[(int)(w1 & 0x1FFFFu) * 64 + c]);
        float h2 = bf2f(hbf[(int)(w2 & 0x1FFFFu) * 64 + c]);
        float h3 = bf2f(hbf[(int)(w3 & 0x1FFFFu) * 64 + c]);
        float h4 = bf2f(hbf[(int)(w4 & 0x1FFFFu) * 64 + c]);
        float h5 = bf2f(hbf[(int)(w5 & 0x1FFFFu) * 64 + c]);
        float h6 = bf2f(hbf[(int)(w6 & 0x1FFFFu) * 64 + c]);
        float h7 = bf2f(hbf[(int)(w7 & 0x1FFFFu) * 64 + c]);
        float al0 = (w0 >> 17) ? 0.5f : 1.0f, al1 = (w1 >> 17) ? 0.5f : 1.0f;
        float al2 = (w2 >> 17) ? 0.5f : 1.0f, al3 = (w3 >> 17) ? 0.5f : 1.0f;
        float al4 = (w4 >> 17) ? 0.5f : 1.0f, al5 = (w5 >> 17) ? 0.5f : 1.0f;
        float al6 = (w6 >> 17) ? 0.5f : 1.0f, al7 = (w7 >> 17) ? 0.5f : 1.0f;
        sm += ((h0 + h1) + (h2 + h3)) + ((h4 + h5) + (h6 + h7));
        sS += (al0 * h0 + al1 * h1 + al2 * h2 + al3 * h3)
            + (al4 * h4 + al5 * h5 + al6 * h6 + al7 * h7);
        sQ += (c0 * h0 + c1 * h1 + c2 * h2 + c3 * h3)
            + (c4 * h4 + c5 * h5 + c6 * h6 + c7 * h7);
        p1 += ((c0 + c1) + (c2 + c3)) + ((c4 + c5) + (c6 + c7));
        p2 += (c0 * c0 + c1 * c1 + c2 * c2 + c3 * c3)
            + (c4 * c4 + c5 * c5 + c6 * c6 + c7 * c7);
    }
    for (; j + 4 <= end; j += 4) {
        unsigned int w0 = (unsigned int)csr[j],     w1 = (unsigned int)csr[j + 1];
        unsigned int w2 = (unsigned int)csr[j + 2], w3 = (unsigned int)csr[j + 3];
        float c0 = cf[j], c1 = cf[j + 1], c2 = cf[j + 2], c3 = cf[j + 3];
        float h0 = bf2f(hbf[(int)(w0 & 0x1FFFFu) * 64 + c]);
        float h1 = bf2f(hbf[(int)(w1 & 0x1FFFFu) * 64 + c]);
        float h2 = bf2f(hbf[(int)(w2 & 0x1FFFFu) * 64 + c]);
        float h3 = bf2f(hbf[(int)(w3 & 0x1FFFFu) * 64 + c]);
        float al0 = (w0 >> 17) ? 0.5f : 1.0f, al1 = (w1 >> 17) ? 0.5f : 1.0f;
        float al2 = (w2 >> 17) ? 0.5f : 1.0f, al3 = (w3 >> 17) ? 0.5f : 1.0f;
        sm += (h0 + h1) + (h2 + h3);
        sS += al0 * h0 + al1 * h1 + al2 * h2 + al3 * h3;
        sQ += c0 * h0 + c1 * h1 + c2 * h2 + c3 * h3;
        p1 += (c0 + c1) + (c2 + c3);
        p2 += c0 * c0 + c1 * c1 + c2 * c2 + c3 * c3;
    }
    for (; j < end; ++j) {
        unsigned int w0 = (unsigned int)csr[j];
        float ha = bf2f(hbf[(int)(w0 & 0x1FFFFu) * 64 + c]);
        float ca = cf[j];
        float ala = (w0 >> 17) ? 0.5f : 1.0f;
        sm += ha;
        sS += ala * ha;
        sQ += ca * ha;
        p1 += ca;
        p2 += ca * ca;
    }
    float r = 0.5f / ((float)dv + 1e-9f);
    float w1o = sS - hv * p1;
    float w2o = sS - fv * p1 - cv * p1 * sm + cv * sQ;
    float w3o = 0.5f * hv + r * (sS - fv * p1 + 0.5f * cv * sQ - cv * hv * p2);
    m0[base] = f2bf(sm);
    W1[base] = f2bf(w1o);
    W2[base] = f2bf(w2o);
    W3a[base] = f2bf(w3o);
    if (c == 0) pp[wid] = make_float2(r * cv * p1, r * cv);
}

// Pass B: gather m0 rows; m1 = W1 + sum c_a m0[a] (in place over W1);
// W4 = W3a - pp.x*m1 + pp.y*U, U = sum c_a^2 m0[a] (in place over W3a).
__global__ void ema_passB_kernel(const int* __restrict__ degi, const int* __restrict__ rs,
                                 const int* __restrict__ csr, const float* __restrict__ cf,
                                 const unsigned short* __restrict__ m0,
                                 unsigned short* __restrict__ W1m1, unsigned short* __restrict__ W3W4,
                                 const float2* __restrict__ pp) {
    int wid = (int)((blockIdx.x * 256 + threadIdx.x) >> 6);
    int c = (int)(threadIdx.x & 63);
    if (wid >= 100000) return;
    int dv = __builtin_amdgcn_readfirstlane(degi[wid]);
    if (dv == 0) return;   // slots already hold m1=0, W4=h from pass A
    int base = wid * 64 + c;
    int j = __builtin_amdgcn_readfirstlane(rs[wid]);
    int end = j + dv;
    float t1 = 0.0f, t2 = 0.0f;
    for (; j + 8 <= end; j += 8) {
        unsigned int w0 = (unsigned int)csr[j],     w1 = (unsigned int)csr[j + 1];
        unsigned int w2 = (unsigned int)csr[j + 2], w3 = (unsigned int)csr[j + 3];
        unsigned int w4 = (unsigned int)csr[j + 4], w5 = (unsigned int)csr[j + 5];
        unsigned int w6 = (unsigned int)csr[j + 6], w7 = (unsigned int)csr[j + 7];
        float c0 = cf[j],     c1 = cf[j + 1], c2 = cf[j + 2], c3 = cf[j + 3];
        float c4 = cf[j + 4], c5 = cf[j + 5], c6 = cf[j + 6], c7 = cf[j + 7];
        float v0 = bf2f(m0[(int)(w0 & 0x1FFFFu) * 64 + c]);
        float v1 = bf2f(m0[(int)(w1 & 0x1FFFFu) * 64 + c]);
        float v2 = bf2f(m0[(int)(w2 & 0x1FFFFu) * 64 + c]);
        float v3 = bf2f(m0[(int)(w3 & 0x1FFFFu) * 64 + c]);
        float v4 = bf2f(m0[(int)(w4 & 0x1FFFFu) * 64 + c]);
        float v5 = bf2f(m0[(int)(w5 & 0x1FFFFu) * 64 + c]);
        float v6 = bf2f(m0[(int)(w6 & 0x1FFFFu) * 64 + c]);
        float v7 = bf2f(m0[(int)(w7 & 0x1FFFFu) * 64 + c]);
        t1 += (c0 * v0 + c1 * v1 + c2 * v2 + c3 * v3)
            + (c4 * v4 + c5 * v5 + c6 * v6 + c7 * v7);
        t2 += (c0 * c0 * v0 + c1 * c1 * v1 + c2 * c2 * v2 + c3 * c3 * v3)
            + (c4 * c4 * v4 + c5 * c5 * v5 + c6 * c6 * v6 + c7 * c7 * v7);
    }
    for (; j + 4 <= end; j += 4) {
        unsigned int w0 = (unsigned int)csr[j],     w1 = (unsigned int)csr[j + 1];
        unsigned int w2 = (unsigned int)csr[j + 2], w3 = (unsigned int)csr[j + 3];
        float c0 = cf[j], c1 = cf[j + 1], c2 = cf[j + 2], c3 = cf[j + 3];
        float v0 = bf2f(m0[(int)(w0 & 0x1FFFFu) * 64 + c]);
        float v1 = bf2f(m0[(int)(w1 & 0x1FFFFu) * 64 + c]);
        float v2 = bf2f(m0[(int)(w2 & 0x1FFFFu) * 64 + c]);
        float v3 = bf2f(m0[(int)(w3 & 0x1FFFFu) * 64 + c]);
        t1 += c0 * v0 + c1 * v1 + c2 * v2 + c3 * v3;
        t2 += c0 * c0 * v0 + c1 * c1 * v1 + c2 * c2 * v2 + c3 * c3 * v3;
    }
    for (; j < end; ++j) {
        unsigned int w0 = (unsigned int)csr[j];
        float ca = cf[j];
        float mv = bf2f(m0[(int)(w0 & 0x1FFFFu) * 64 + c]);
        t1 += ca * mv;
        t2 += ca * ca * mv;
    }
    float2 ppv = pp[wid];
    float m1 = bf2f(W1m1[base]) + t1;
    float w4 = bf2f(W3W4[base]) - ppv.x * m1 + ppv.y * t2;
    W1m1[base] = f2bf(m1);
    W3W4[base] = f2bf(w4);
}

// Pass C: gather m1 rows; m2 = W2 + sum c_a m1[a] (in place over W2).
__global__ void ema_passC_kernel(const int* __restrict__ degi, const int* __restrict__ rs,
                                 const int* __restrict__ csr, const float* __restrict__ cf,
                                 const unsigned short* __restrict__ m1,
                                 unsigned short* __restrict__ W2m2) {
    int wid = (int)((blockIdx.x * 256 + threadIdx.x) >> 6);
    int c = (int)(threadIdx.x & 63);
    if (wid >= 100000) return;
    int dv = __builtin_amdgcn_readfirstlane(degi[wid]);
    if (dv == 0) return;   // slot already holds m2=0
    int base = wid * 64 + c;
    int j = __builtin_amdgcn_readfirstlane(rs[wid]);
    int end = j + dv;
    float t = 0.0f;
    for (; j + 8 <= end; j += 8) {
        unsigned int w0 = (unsigned int)csr[j],     w1 = (unsigned int)csr[j + 1];
        unsigned int w2 = (unsigned int)csr[j + 2], w3 = (unsigned int)csr[j + 3];
        unsigned int w4 = (unsigned int)csr[j + 4], w5 = (unsigned int)csr[j + 5];
        unsigned int w6 = (unsigned int)csr[j + 6], w7 = (unsigned int)csr[j + 7];
        float c0 = cf[j],     c1 = cf[j + 1], c2 = cf[j + 2], c3 = cf[j + 3];
        float c4 = cf[j + 4], c5 = cf[j + 5], c6 = cf[j + 6], c7 = cf[j + 7];
        float v0 = bf2f(m1[(int)(w0 & 0x1FFFFu) * 64 + c]);
        float v1 = bf2f(m1[(int)(w1 & 0x1FFFFu) * 64 + c]);
        float v2 = bf2f(m1[(int)(w2 & 0x1FFFFu) * 64 + c]);
        float v3 = bf2f(m1[(int)(w3 & 0x1FFFFu) * 64 + c]);
        float v4 = bf2f(m1[(int)(w4 & 0x1FFFFu) * 64 + c]);
        float v5 = bf2f(m1[(int)(w5 & 0x1FFFFu) * 64 + c]);
        float v6 = bf2f(m1[(int)(w6 & 0x1FFFFu) * 64 + c]);
        float v7 = bf2f(m1[(int)(w7 & 0x1FFFFu) * 64 + c]);
        t += (c0 * v0 + c1 * v1 + c2 * v2 + c3 * v3)
           + (c4 * v4 + c5 * v5 + c6 * v6 + c7 * v7);
    }
    for (; j + 4 <= end; j += 4) {
        unsigned int w0 = (unsigned int)csr[j],     w1 = (unsigned int)csr[j + 1];
        unsigned int w2 = (unsigned int)csr[j + 2], w3 = (unsigned int)csr[j + 3];
        float c0 = cf[j], c1 = cf[j + 1], c2 = cf[j + 2], c3 = cf[j + 3];
        float v0 = bf2f(m1[(int)(w0 & 0x1FFFFu) * 64 + c]);
        float v1 = bf2f(m1[(int)(w1 & 0x1FFFFu) * 64 + c]);
        float v2 = bf2f(m1[(int)(w2 & 0x1FFFFu) * 64 + c]);
        float v3 = bf2f(m1[(int)(w3 & 0x1FFFFu) * 64 + c]);
        t += c0 * v0 + c1 * v1 + c2 * v2 + c3 * v3;
    }
    for (; j < end; ++j) {
        unsigned int w0 = (unsigned int)csr[j];
        t += cf[j] * bf2f(m1[(int)(w0 & 0x1FFFFu) * 64 + c]);
    }
    float m2v = bf2f(W2m2[base]) + t;
    W2m2[base] = f2bf(m2v);
}

// Pass D (identifier kernel): gather m2 rows; y = W4 + r*sum c_a m2[a];
// out = x + relu(y). Overwrites all of d_out (m0 + cf regions are dead;
// reads cfD, the copy in hbf's slot).
__global__ void GraphEMALayer_18133351924067_kernel(
    const int* __restrict__ degi, const int* __restrict__ rs,
    const int* __restrict__ csr, const float* __restrict__ cfD,
    const unsigned short* __restrict__ m2, const unsigned short* __restrict__ W4,
    const float* __restrict__ x, float* __restrict__ out) {
    int wid = (int)((blockIdx.x * 256 + threadIdx.x) >> 6);
    int c = (int)(threadIdx.x & 63);
    if (wid >= 100000) return;
    int dv = __builtin_amdgcn_readfirstlane(degi[wid]);
    int base = wid * 64 + c;
    float xv = x[base];
    float y = bf2f(W4[base]);
    if (dv > 0) {
        int j = __builtin_amdgcn_readfirstlane(rs[wid]);
        int end = j + dv;
        float t = 0.0f;
        for (; j + 8 <= end; j += 8) {
            unsigned int w0 = (unsigned int)csr[j],     w1 = (unsigned int)csr[j + 1];
            unsigned int w2 = (unsigned int)csr[j + 2], w3 = (unsigned int)csr[j + 3];
            unsigned int w4 = (unsigned int)csr[j + 4], w5 = (unsigned int)csr[j + 5];
            unsigned int w6 = (unsigned int)csr[j + 6], w7 = (unsigned int)csr[j + 7];
            float c0 = cfD[j],     c1 = cfD[j + 1], c2 = cfD[j + 2], c3 = cfD[j + 3];
            float c4 = cfD[j + 4], c5 = cfD[j + 5], c6 = cfD[j + 6], c7 = cfD[j + 7];
            float v0 = bf2f(m2[(int)(w0 & 0x1FFFFu) * 64 + c]);
            float v1 = bf2f(m2[(int)(w1 & 0x1FFFFu) * 64 + c]);
            float v2 = bf2f(m2[(int)(w2 & 0x1FFFFu) * 64 + c]);
            float v3 = bf2f(m2[(int)(w3 & 0x1FFFFu) * 64 + c]);
            float v4 = bf2f(m2[(int)(w4 & 0x1FFFFu) * 64 + c]);
            float v5 = bf2f(m2[(int)(w5 & 0x1FFFFu) * 64 + c]);
            float v6 = bf2f(m2[(int)(w6 & 0x1FFFFu) * 64 + c]);
            float v7 = bf2f(m2[(int)(w7 & 0x1FFFFu) * 64 + c]);
            t += (c0 * v0 + c1 * v1 + c2 * v2 + c3 * v3)
               + (c4 * v4 + c5 * v5 + c6 * v6 + c7 * v7);
        }
        for (; j + 4 <= end; j += 4) {
            unsigned int w0 = (unsigned int)csr[j],     w1 = (unsigned int)csr[j + 1];
            unsigned int w2 = (unsigned int)csr[j + 2], w3 = (unsigned int)csr[j + 3];
            float c0 = cfD[j], c1 = cfD[j + 1], c2 = cfD[j + 2], c3 = cfD[j + 3];
            float v0 = bf2f(m2[(int)(w0 & 0x1FFFFu) * 64 + c]);
            float v1 = bf2f(m2[(int)(w1 & 0x1FFFFu) * 64 + c]);
            float v2 = bf2f(m2[(int)(w2 & 0x1FFFFu) * 64 + c]);
            float v3 = bf2f(m2[(int)(w3 & 0x1FFFFu) * 64 + c]);
            t += c0 * v0 + c1 * v1 + c2 * v2 + c3 * v3;
        }
        for (; j < end; ++j) {
            unsigned int w0 = (unsigned int)csr[j];
            t += cfD[j] * bf2f(m2[(int)(w0 & 0x1FFFFu) * 64 + c]);
        }
        float r = 0.5f / ((float)dv + 1e-9f);
        y += r * t;
    }
    if (y < 0.0f) y = 0.0f;
    out[base] = xv + y;
}

extern "C" void kernel_launch(void* const* d_in, const int* in_sizes, int n_in,
                              void* d_out, int out_size, void* d_ws, size_t ws_size,
                              hipStream_t stream) {
    (void)in_sizes; (void)n_in; (void)out_size; (void)ws_size;

    const float* x    = (const float*)d_in[0];
    const int*   ei   = (const int*)d_in[1];
    const float* W    = (const float*)d_in[2];
    const float* bias = (const float*)d_in[3];
    float* out = (float*)d_out;
    unsigned short* m0 = (unsigned short*)d_out;   // first 12.8 MB, dead before D
    float* cf = (float*)((char*)d_out + 12800000); // 6.4 MB, dead before D

    char* ws = (char*)d_ws;
    unsigned short* hbf  = (unsigned short*)(ws);             // 12,800,000 B
    unsigned short* W1m1 = (unsigned short*)(ws + 12800000);  // 12,800,000 B
    unsigned short* W2m2 = (unsigned short*)(ws + 25600000);  // 12,800,000 B
    unsigned short* W3W4 = (unsigned short*)(ws + 38400000);  // 12,800,000 B
    int* degi = (int*)(ws + 51200000);                        //    400,000 B
    int* rs   = (int*)(ws + 51600000);                        //    400,000 B
    float2* pp   = (float2*)(ws + 52800000);                  //    800,000 B
    int* csr  = (int*)(ws + 53600000);                        //  6,400,000 B
    int* bbase = (int*)(ws + 60000000);                       //      1,568 B
    int* btot  = (int*)(ws + 60002048);                       //      1,564 B

    // CSR-build scratch, both dead before pass A writes them:
    unsigned int* stage = (unsigned int*)(ws + 12800000);     // aliases W1m1, 6.4 MB
    int* hcnt = (int*)(ws + 25600000);                        // aliases W2m2, 611,524 B
    float* cfD = (float*)(ws);                                // aliases hbf (dead after A)

    int eb = (100000 * 64 + 255) / 256;   // 25000 blocks: wave-per-node grids
    int nb = (100000 + 255) / 256;        //   391 blocks: per-bucket grids
    int pb = (1600000 + 4095) / 4096;     //   391 blocks: partition grids
    int gb = (100000 + 31) / 32;          //  3125 blocks: gemm (32 nodes/block)
    int db = (1600000 + 255) / 256;       //  6250 blocks: cfgen
    int cb = (400000 + 255) / 256;        //  1563 blocks: cf copy (float4)

    ema_gemm_kernel<<<gb, 256, 0, stream>>>(x, W, bias, hbf);

    ema_hist_kernel<<<pb, 256, 0, stream>>>(ei, hcnt);
    ema_bscan_row_kernel<<<391, 512, 0, stream>>>(hcnt, btot);
    ema_bscan_base_kernel<<<1, 512, 0, stream>>>(btot, bbase);
    ema_scatter_kernel<<<pb, 256, 0, stream>>>(ei, hcnt, bbase, stage);
    ema_fillcsr_count_kernel<<<nb, 256, 0, stream>>>(bbase, stage, degi, rs);
    ema_fillcsr_write_kernel<<<nb, 256, 0, stream>>>(rs, stage, degi, csr);
    ema_cfgen_kernel<<<db, 256, 0, stream>>>(csr, cf);

    ema_passA_kernel<<<eb, 256, 0, stream>>>(degi, rs, csr, cf, hbf,
                                             m0, W1m1, W2m2, W3W4, pp);
    ema_cfcopy_kernel<<<cb, 256, 0, stream>>>((const float4*)cf, (float4*)cfD);
    ema_passB_kernel<<<eb, 256, 0, stream>>>(degi, rs, csr, cf, m0,
                                             W1m1, W3W4, pp);
    ema_passC_kernel<<<eb, 256, 0, stream>>>(degi, rs, csr, cf, W1m1, W2m2);
    GraphEMALayer_18133351924067_kernel<<<eb, 256, 0, stream>>>(
        degi, rs, csr, cfD, W2m2, W3W4, x, out);
}